// Round 2
// baseline (268.391 us; speedup 1.0000x reference)
//
#include <hip/hip_runtime.h>
#include <hip/hip_bf16.h>
#include <cstdint>
#include <cstddef>

// B=2, S=4096, HID=512, H=8, D_K=64.
// cvt(f32->bf16, scale log2e/ln64 folded into Wq) -> QKV proj (bf16 MFMA;
// Q,K stored as plain [kM][512]; V stored transposed [bh][d][s]) ->
// flash attention v9:
//   * 32x32x16 MFMA (halves LDS frag bytes/FLOP vs 16x16x32)
//   * wave owns 32 q; 4-wave (256 thr) blocks; keys split across 2 blocks
//     (grid z=2) -> 1024 blocks = 4 blocks/CU = 4 waves/SIMD
//   * P stays in registers: cvt_pk_bf16_f32 + v_permlane32_swap builds the
//     PV B-frag directly from the 32x32 C-layout (no P LDS, no barrier)
//   * K/V staged via global_load_lds (16B), XOR-swizzled via pre-swizzled
//     global source (LDS dest stays linear), double-buffered, 1 sync/tile
//   * mask bias pre-loaded into MFMA C operand; no running max
//   * partial O (bf16) + partial sum -> workspace; combine kernel finishes
// -> output proj (f32 out).

namespace {

constexpr int kB = 2, kS = 4096, kHid = 512, kH = 8, kDk = 64;
constexpr int kBH = kB * kH;   // 16
constexpr int kM = kB * kS;    // 8192

typedef __attribute__((ext_vector_type(8))) short short8;
typedef __attribute__((ext_vector_type(4))) float floatx4;
typedef __attribute__((ext_vector_type(16))) float floatx16;
typedef __attribute__((ext_vector_type(4))) unsigned int uintx4;
typedef unsigned short u16;

__device__ __forceinline__ u16 bf16rne(float f) {
    uint32_t u = __float_as_uint(f);
    u += 0x7fffu + ((u >> 16) & 1u);
    return (u16)(u >> 16);
}
__device__ __forceinline__ uint32_t pk2(float lo, float hi) {
#if __has_builtin(__builtin_amdgcn_cvt_pk_bf16_f32)
    typedef __attribute__((ext_vector_type(2))) __bf16 bf2;
    bf2 h = __builtin_amdgcn_cvt_pk_bf16_f32(lo, hi);
    return __builtin_bit_cast(uint32_t, h);
#else
    return ((uint32_t)bf16rne(hi) << 16) | (uint32_t)bf16rne(lo);
#endif
}
__device__ __forceinline__ float fexp2(float x) {
#if __has_builtin(__builtin_amdgcn_exp2f)
    return __builtin_amdgcn_exp2f(x);
#else
    return exp2f(x);
#endif
}
__device__ __forceinline__ float bf2f(u16 v) {
    return __uint_as_float((uint32_t)v << 16);
}
// swap upper 32 lanes of a with lower 32 lanes of b
__device__ __forceinline__ void plswap(uint32_t& a, uint32_t& b) {
#if __has_builtin(__builtin_amdgcn_permlane32_swap)
    typedef __attribute__((ext_vector_type(2))) unsigned int uint2v;
    uint2v r = __builtin_amdgcn_permlane32_swap(a, b, false, false);
    a = r[0]; b = r[1];
#else
    asm volatile("v_permlane32_swap_b32 %0, %1" : "+v"(a), "+v"(b));
#endif
}
__device__ __forceinline__ void gload16(const void* g, void* l) {
    __builtin_amdgcn_global_load_lds(
        (const __attribute__((address_space(1))) void*)g,
        (__attribute__((address_space(3))) void*)l, 16, 0, 0);
}

// ---- fused f32->bf16 conversion: q/k/v (z<3) and weights -------------------
__global__ __launch_bounds__(256) void cvt_qw(const float* __restrict__ q,
    const float* __restrict__ k, const float* __restrict__ v,
    const float* __restrict__ w0, const float* __restrict__ w1,
    const float* __restrict__ w2, const float* __restrict__ w3,
    u16* __restrict__ xall, u16* __restrict__ wall) {
    const int bx = blockIdx.x;
    if (bx < 12288) {           // q/k/v: 3 x 4096 blocks
        int z = bx >> 12;
        size_t i = (size_t)(bx & 4095) * 256 + threadIdx.x;
        const float* src = z == 0 ? q : (z == 1 ? k : v);
        float4 f = ((const float4*)src)[i];
        ushort4 o;
        o.x = bf16rne(f.x); o.y = bf16rne(f.y);
        o.z = bf16rne(f.z); o.w = bf16rne(f.w);
        ((ushort4*)(xall + (size_t)z * kM * kHid))[i] = o;
    } else {                    // weights: 4 x 256 blocks
        int r = bx - 12288;
        int z = r >> 8;
        size_t i = (size_t)(r & 255) * 256 + threadIdx.x;
        const float* src = z == 0 ? w0 : (z == 1 ? w1 : (z == 2 ? w2 : w3));
        float sc = (z == 0)
            ? (float)(1.4426950408889634 / (6.0 * 0.6931471805599453))  // log2e/ln64
            : 1.0f;
        float4 f = ((const float4*)src)[i];
        ushort4 o;
        o.x = bf16rne(f.x * sc); o.y = bf16rne(f.y * sc);
        o.z = bf16rne(f.z * sc); o.w = bf16rne(f.w * sc);
        ((ushort4*)(wall + (size_t)z * kHid * kHid))[i] = o;
    }
}

// ---- mask -> float bias (0 or -1e30) ---------------------------------------
__global__ __launch_bounds__(256) void cvt_mask(const int* __restrict__ mask,
    float* __restrict__ fb) {
    int i = blockIdx.x * 256 + threadIdx.x;
    fb[i] = mask[i] ? 0.0f : -1e30f;
}

// ---- QKV projection: out = x @ W^T; block 128x128, wave 64x64 --------------
__global__ __launch_bounds__(256, 3) void proj(const u16* __restrict__ xall,
    const u16* __restrict__ wall, u16* __restrict__ qp, u16* __restrict__ kp,
    u16* __restrict__ vt) {
    __shared__ float smt[4][16][68];
    const int z = blockIdx.z;
    const u16* x = xall + (size_t)z * kM * kHid;
    const u16* w = wall + (size_t)z * kHid * kHid;
    const int wv = threadIdx.x >> 6, lane = threadIdx.x & 63;
    const int quad = lane >> 4, l16 = lane & 15;
    const int mb = blockIdx.y * 128 + (wv >> 1) * 64;
    const int nb = blockIdx.x * 128 + (wv & 1) * 64;
    floatx4 acc[4][4] = {};
    const u16* xr = x + (size_t)(mb + l16) * kHid + quad * 8;
    const u16* wr = w + (size_t)(nb + l16) * kHid + quad * 8;
    for (int k0 = 0; k0 < kHid; k0 += 32) {
        short8 a[4], bt[4];
#pragma unroll
        for (int i = 0; i < 4; i++)
            a[i] = *(const short8*)(xr + (size_t)i * 16 * kHid + k0);
#pragma unroll
        for (int t = 0; t < 4; t++)
            bt[t] = *(const short8*)(wr + (size_t)t * 16 * kHid + k0);
#pragma unroll
        for (int i = 0; i < 4; i++)
#pragma unroll
        for (int t = 0; t < 4; t++)
            acc[i][t] = __builtin_amdgcn_mfma_f32_16x16x32_bf16(a[i], bt[t], acc[i][t], 0, 0, 0);
    }
    if (z < 2) {
        u16* dst = (z == 0) ? qp : kp;
        const int row16 = lane >> 2, cseg = (lane & 3) * 16;
#pragma unroll
        for (int i = 0; i < 4; i++) {
#pragma unroll
            for (int t = 0; t < 4; t++)
#pragma unroll
            for (int r = 0; r < 4; r++)
                smt[wv][quad * 4 + r][t * 16 + l16] = acc[i][t][r];
            __builtin_amdgcn_wave_barrier();
            const float* rp = &smt[wv][row16][cseg];
            float4 f0 = *(const float4*)(rp);
            float4 f1 = *(const float4*)(rp + 4);
            float4 f2 = *(const float4*)(rp + 8);
            float4 f3 = *(const float4*)(rp + 12);
            uint4 o0, o1;
            o0.x = pk2(f0.x, f0.y); o0.y = pk2(f0.z, f0.w);
            o0.z = pk2(f1.x, f1.y); o0.w = pk2(f1.z, f1.w);
            o1.x = pk2(f2.x, f2.y); o1.y = pk2(f2.z, f2.w);
            o1.z = pk2(f3.x, f3.y); o1.w = pk2(f3.z, f3.w);
            u16* dp = dst + (size_t)(mb + i * 16 + row16) * kHid + nb + cseg;
            *(uint4*)dp = o0;
            *(uint4*)(dp + 8) = o1;
            __builtin_amdgcn_wave_barrier();
        }
    } else {
#pragma unroll
        for (int i = 0; i < 4; i++)
#pragma unroll
        for (int t = 0; t < 4; t++) {
            int m0 = mb + i * 16 + quad * 4;
            int n = nb + t * 16 + l16;
            int b = m0 >> 12, s = m0 & (kS - 1);
            int h = n >> 6,   d = n & (kDk - 1);
            ushort4 o;
            o.x = bf16rne(acc[i][t][0]); o.y = bf16rne(acc[i][t][1]);
            o.z = bf16rne(acc[i][t][2]); o.w = bf16rne(acc[i][t][3]);
            *(ushort4*)(vt + ((size_t)(b * kH + h) * kDk + d) * kS + s) = o;
        }
    }
}

// ---- flash attention v9 ----------------------------------------------------
// grid (kS/128, kBH, 2); block 256 = 4 waves, wave owns 32 q (32x32 MFMA).
// kz block handles key-tiles {kz, kz+2, ...} (32 of 64). Partial out.
__global__ __launch_bounds__(256, 4) void attn(const u16* __restrict__ qp,
    const u16* __restrict__ kp, const u16* __restrict__ vt,
    const float* __restrict__ fbias, u16* __restrict__ ows,
    float* __restrict__ rsws) {
    union SmT {
        struct { u16 K[2][64][64]; u16 V[2][64][64]; } s;   // 32768 B
        float ep[4][32][33];                                 // 16896 B
    };
    __shared__ __align__(16) SmT sm;
    const int tid = threadIdx.x;
    const int wv = tid >> 6, l = tid & 63;
    const int hf = l >> 5, q32 = l & 31, l7 = l & 7;
    const int bh = blockIdx.y, b = bh >> 3, h = bh & 7;
    const int kz = blockIdx.z;
    const int q0 = blockIdx.x * 128 + wv * 32;
    const u16* Qb = qp + (size_t)b * kS * kHid + h * 64;   // [s][512] + h*64
    const u16* Kb = kp + (size_t)b * kS * kHid + h * 64;
    const u16* Vb = vt + (size_t)bh * kDk * kS;            // [d][s]
    const float* fm = fbias + b * kS;

    // Q frags: row = q0+q32, k-chunk m*16 + hf*8 (32x32x16 A/B layout)
    short8 qf[4];
#pragma unroll
    for (int m = 0; m < 4; m++)
        qf[m] = *(const short8*)(Qb + (size_t)(q0 + q32) * kHid + m * 16 + hf * 8);

    floatx16 O0 = {}, O1 = {};   // d 0-31 / 32-63, C-layout
    float rs = 0.0f;

    // staging: per wave 4x global_load_lds(16B). Global col pre-swizzled so
    // linear LDS dest (base + lane*16) realizes chunk_phys = chunk ^ (row&7).
    const int srow = l >> 3;                  // 0..7 within 8-row group
    const int swcol = (l7 ^ srow) * 8;        // swizzled source col (u16)
    auto stage = [&](int itn, int ph) {
        const size_t kr = (size_t)(itn * 64 + wv * 8 + srow);
        gload16(Kb + kr * kHid + swcol,        &sm.s.K[ph][wv * 8][0]);
        gload16(Kb + (kr + 32) * kHid + swcol, &sm.s.K[ph][wv * 8 + 32][0]);
        const size_t vr = (size_t)(wv * 8 + srow) * kS + itn * 64 + swcol;
        gload16(Vb + vr,                       &sm.s.V[ph][wv * 8][0]);
        gload16(Vb + (size_t)32 * kS + vr,     &sm.s.V[ph][wv * 8 + 32][0]);
    };

    stage(kz, 0);
    __syncthreads();

    for (int s = 0; s < 32; ++s) {
        const int it = kz + 2 * s, ph = s & 1, kt = it * 64;
        if (s < 31) stage(it + 2, ph ^ 1);
#pragma unroll
        for (int ks = 0; ks < 2; ++ks) {
            // K frags: row = ks*32+q32, chunk_phys = (2m+hf)^(row&7)
            short8 kf[4];
#pragma unroll
            for (int m = 0; m < 4; m++)
                kf[m] = *(const short8*)&sm.s.K[ph][ks * 32 + q32][((2 * m + hf) ^ l7) * 8];
            // V frags: row = ds*32+q32, chunk = ks*4 + tt*2 + hf
            short8 vf[2][2];
#pragma unroll
            for (int ds = 0; ds < 2; ds++)
#pragma unroll
            for (int tt = 0; tt < 2; tt++)
                vf[ds][tt] = *(const short8*)&sm.s.V[ph][ds * 32 + q32][((ks * 4 + tt * 2 + hf) ^ l7) * 8];
            // C-init = mask bias at key rows (reg r -> key (r&3)+8*(r>>2)+4*hf)
            floatx16 st;
            {
                const float* fp = fm + kt + ks * 32 + 4 * hf;
                float4 g0 = *(const float4*)(fp);
                float4 g1 = *(const float4*)(fp + 8);
                float4 g2 = *(const float4*)(fp + 16);
                float4 g3 = *(const float4*)(fp + 24);
                st[0] = g0.x;  st[1] = g0.y;  st[2] = g0.z;  st[3] = g0.w;
                st[4] = g1.x;  st[5] = g1.y;  st[6] = g1.z;  st[7] = g1.w;
                st[8] = g2.x;  st[9] = g2.y;  st[10] = g2.z; st[11] = g2.w;
                st[12] = g3.x; st[13] = g3.y; st[14] = g3.z; st[15] = g3.w;
            }
            // S^T = K*Q^T + bias
#pragma unroll
            for (int m = 0; m < 4; m++)
                st = __builtin_amdgcn_mfma_f32_32x32x16_bf16(kf[m], qf[m], st, 0, 0, 0);
            // exp2 + sum
            float xx[16];
#pragma unroll
            for (int r = 0; r < 16; r++) xx[r] = fexp2(st[r]);
            rs += (((xx[0] + xx[1]) + (xx[2] + xx[3])) + ((xx[4] + xx[5]) + (xx[6] + xx[7])))
                + (((xx[8] + xx[9]) + (xx[10] + xx[11])) + ((xx[12] + xx[13]) + (xx[14] + xx[15])));
            // pack + permlane32_swap -> PV B-frags (keys lane-local, no LDS)
            uint32_t w00 = pk2(xx[0], xx[1]),   w01 = pk2(xx[2], xx[3]);
            uint32_t w10 = pk2(xx[4], xx[5]),   w11 = pk2(xx[6], xx[7]);
            uint32_t w20 = pk2(xx[8], xx[9]),   w21 = pk2(xx[10], xx[11]);
            uint32_t w30 = pk2(xx[12], xx[13]), w31 = pk2(xx[14], xx[15]);
            plswap(w00, w10); plswap(w01, w11);   // tt=0: slots {0,1,2,3}
            plswap(w20, w30); plswap(w21, w31);   // tt=1
            uintx4 t0 = {w00, w01, w10, w11};
            uintx4 t1 = {w20, w21, w30, w31};
            short8 bf0 = __builtin_bit_cast(short8, t0);
            short8 bf1 = __builtin_bit_cast(short8, t1);
            // O^T += V^T * P^T
            O0 = __builtin_amdgcn_mfma_f32_32x32x16_bf16(vf[0][0], bf0, O0, 0, 0, 0);
            O0 = __builtin_amdgcn_mfma_f32_32x32x16_bf16(vf[0][1], bf1, O0, 0, 0, 0);
            O1 = __builtin_amdgcn_mfma_f32_32x32x16_bf16(vf[1][0], bf0, O1, 0, 0, 0);
            O1 = __builtin_amdgcn_mfma_f32_32x32x16_bf16(vf[1][1], bf1, O1, 0, 0, 0);
        }
        __syncthreads();
    }

    // partial row-sum: halves hold disjoint keys -> one swap-add
    rs += __shfl_xor(rs, 32);
    if (hf == 0)
        rsws[((size_t)kz * kBH + bh) * kS + q0 + q32] = rs;

    // partial O (raw, bf16) via per-wave LDS transpose; 2 passes (d 0-31, 32-63)
    u16* Ob = ows + (((size_t)kz * kBH + bh) * kS + q0) * kDk;
#pragma unroll
    for (int ds = 0; ds < 2; ds++) {
#pragma unroll
        for (int r = 0; r < 16; r++)
            sm.ep[wv][q32][(r & 3) + 8 * (r >> 2) + 4 * hf] = (ds == 0) ? O0[r] : O1[r];
        __builtin_amdgcn_wave_barrier();
        {
            const int qq = l >> 1, c0 = (l & 1) * 16;
            float f[16];
#pragma unroll
            for (int j = 0; j < 16; j++) f[j] = sm.ep[wv][qq][c0 + j];
            uint4 o0, o1;
            o0.x = pk2(f[0], f[1]);   o0.y = pk2(f[2], f[3]);
            o0.z = pk2(f[4], f[5]);   o0.w = pk2(f[6], f[7]);
            o1.x = pk2(f[8], f[9]);   o1.y = pk2(f[10], f[11]);
            o1.z = pk2(f[12], f[13]); o1.w = pk2(f[14], f[15]);
            u16* dp = Ob + (size_t)qq * kDk + ds * 32 + c0;
            *(uint4*)dp = o0;
            *(uint4*)(dp + 8) = o1;
        }
        __builtin_amdgcn_wave_barrier();
    }
}

// ---- combine: out = (O_part0 + O_part1) / (rs0 + rs1), bf16 ---------------
__global__ __launch_bounds__(256) void combine(const u16* __restrict__ ows,
    const float* __restrict__ rsws, u16* __restrict__ xo) {
    size_t i = (size_t)blockIdx.x * 256 + threadIdx.x;   // 524288 total
    const int d8 = (int)(i & 7);
    const int s  = (int)((i >> 3) & (kS - 1));
    const int bh = (int)(i >> 15);
    const int b = bh >> 3, h = bh & 7;
    const size_t base = ((size_t)bh * kS + s) * kDk + d8 * 8;
    short8 a = *(const short8*)(ows + base);
    short8 c = *(const short8*)(ows + (size_t)kBH * kS * kDk + base);
    float r = rsws[(size_t)bh * kS + s] + rsws[(size_t)kBH * kS + (size_t)bh * kS + s];
    float inv = 1.0f / r;
    float e[8];
#pragma unroll
    for (int j = 0; j < 8; j++)
        e[j] = (bf2f((u16)a[j]) + bf2f((u16)c[j])) * inv;
    uint4 o;
    o.x = pk2(e[0], e[1]); o.y = pk2(e[2], e[3]);
    o.z = pk2(e[4], e[5]); o.w = pk2(e[6], e[7]);
    *(uint4*)(xo + ((size_t)b * kS + s) * kHid + h * 64 + d8 * 8) = o;
}

// ---- output projection: out = X @ Wo^T; block 128x128, wave 64x64, f32 out -
__global__ __launch_bounds__(256, 3) void oproj(const u16* __restrict__ x,
    const u16* __restrict__ w, float* __restrict__ out) {
    const int wv = threadIdx.x >> 6, lane = threadIdx.x & 63;
    const int quad = lane >> 4, l16 = lane & 15;
    const int mb = blockIdx.y * 128 + (wv >> 1) * 64;
    const int nb = blockIdx.x * 128 + (wv & 1) * 64;
    floatx4 acc[4][4] = {};
    const u16* xr = x + (size_t)(mb + l16) * kHid + quad * 8;
    const u16* wr = w + (size_t)(nb + l16) * kHid + quad * 8;
    for (int k0 = 0; k0 < kHid; k0 += 32) {
        short8 a[4], bt[4];
#pragma unroll
        for (int i = 0; i < 4; i++)
            a[i] = *(const short8*)(xr + (size_t)i * 16 * kHid + k0);
#pragma unroll
        for (int t = 0; t < 4; t++)
            bt[t] = *(const short8*)(wr + (size_t)t * 16 * kHid + k0);
#pragma unroll
        for (int i = 0; i < 4; i++)
#pragma unroll
        for (int t = 0; t < 4; t++)
            acc[i][t] = __builtin_amdgcn_mfma_f32_16x16x32_bf16(a[i], bt[t], acc[i][t], 0, 0, 0);
    }
#pragma unroll
    for (int i = 0; i < 4; i++)
#pragma unroll
    for (int t = 0; t < 4; t++)
#pragma unroll
    for (int r = 0; r < 4; r++) {
        int m = mb + i * 16 + quad * 4 + r;
        int n = nb + t * 16 + l16;
        out[(size_t)m * kHid + n] = acc[i][t][r];
    }
}

} // namespace

extern "C" void kernel_launch(void* const* d_in, const int* in_sizes, int n_in,
                              void* d_out, int out_size, void* d_ws, size_t ws_size,
                              hipStream_t stream) {
    const float* q  = (const float*)d_in[0];
    const float* k  = (const float*)d_in[1];
    const float* v  = (const float*)d_in[2];
    const int* mask = (const int*)d_in[3];
    const float* w0 = (const float*)d_in[4];
    const float* w1 = (const float*)d_in[5];
    const float* w2 = (const float*)d_in[6];
    const float* w3 = (const float*)d_in[7];
    float* out = (float*)d_out;

    // ws (u16 units): xall(3*4.19M) | wall(4*256K) | Q | K | V^T  (~52.4 MB)
    // After proj, xall is dead and is reused:
    //   ows  (bf16 partial O [2][16][4096][64], 16.78 MB) at xall[0]
    //   fbias (f32, 32 KB) at xall + 2*kM*kHid  (byte 16.78M, clear of ows)
    //   rsws (f32 [2][16][4096], 512 KB) after fbias
    // xo (combine output) reuses qp (dead after attn).
    u16* ws   = (u16*)d_ws;
    u16* xall = ws;
    u16* wall = xall + (size_t)3 * kM * kHid;
    u16* qp   = wall + (size_t)4 * kHid * kHid;
    u16* kp   = qp + (size_t)kBH * kS * kDk;
    u16* vt   = kp + (size_t)kBH * kS * kDk;
    u16* ows  = xall;
    float* fbias = (float*)(xall + (size_t)2 * kM * kHid);
    float* rsws  = fbias + (size_t)kB * kS;
    u16* xo   = qp;

    dim3 blk(256);
    cvt_qw <<<dim3(13312), blk, 0, stream>>>(q, k, v, w0, w1, w2, w3, xall, wall);
    proj   <<<dim3(kHid / 128, kM / 128, 3), blk, 0, stream>>>(xall, wall, qp, kp, vt);
    cvt_mask<<<dim3(kB * kS / 256), blk, 0, stream>>>(mask, fbias);
    attn   <<<dim3(kS / 128, kBH, 2), blk, 0, stream>>>(qp, kp, vt, fbias, ows, rsws);
    combine<<<dim3(2048), blk, 0, stream>>>(ows, rsws, xo);
    oproj  <<<dim3(kHid / 128, kM / 128), blk, 0, stream>>>(
        xo, wall + (size_t)3 * kHid * kHid, out);
}

// Round 3
// 264.853 us; speedup vs baseline: 1.0134x; 1.0134x over previous
//
#include <hip/hip_runtime.h>
#include <hip/hip_bf16.h>
#include <cstdint>
#include <cstddef>

// B=2, S=4096, HID=512, H=8, D_K=64.
// cvt(f32->bf16, scale log2e/ln64 folded into Wq) -> QKV proj (bf16 MFMA;
// Q,K stored as plain [kM][512]; V stored transposed [bh][d][s]) ->
// flash attention v10:
//   * 32x32x16 MFMA; wave owns 64 q (2 q-tiles) -> K/V frag reads + bias
//     amortized over 2x MFMAs (v9's LDS-read pipe was ~40% of runtime)
//   * 256 q/block (4 waves), keys split across 2 blocks -> 512 blocks,
//     2 blocks/CU; dual q-tile chains give in-wave ILP at 2 waves/SIMD
//   * XCD-pinned bh decode: all 32 blocks of a bh land on one XCD ->
//     K/V re-reads served from local 4MB L2 (not L3)
//   * P stays in registers (cvt_pk + permlane32_swap); no P LDS
//   * K/V staged via global_load_lds (16B), XOR-swizzled via pre-swizzled
//     per-lane global source (LDS dest linear), double-buffered
//   * mask bias as MFMA C operand; no running max (masked -> exp2(-1e30)=0)
//   * partial O (bf16) + partial sum -> workspace; combine kernel finishes
// -> output proj (f32 out).

namespace {

constexpr int kB = 2, kS = 4096, kHid = 512, kH = 8, kDk = 64;
constexpr int kBH = kB * kH;   // 16
constexpr int kM = kB * kS;    // 8192

typedef __attribute__((ext_vector_type(8))) short short8;
typedef __attribute__((ext_vector_type(4))) float floatx4;
typedef __attribute__((ext_vector_type(16))) float floatx16;
typedef __attribute__((ext_vector_type(4))) unsigned int uintx4;
typedef unsigned short u16;

__device__ __forceinline__ u16 bf16rne(float f) {
    uint32_t u = __float_as_uint(f);
    u += 0x7fffu + ((u >> 16) & 1u);
    return (u16)(u >> 16);
}
__device__ __forceinline__ uint32_t pk2(float lo, float hi) {
#if __has_builtin(__builtin_amdgcn_cvt_pk_bf16_f32)
    typedef __attribute__((ext_vector_type(2))) __bf16 bf2;
    bf2 h = __builtin_amdgcn_cvt_pk_bf16_f32(lo, hi);
    return __builtin_bit_cast(uint32_t, h);
#else
    return ((uint32_t)bf16rne(hi) << 16) | (uint32_t)bf16rne(lo);
#endif
}
__device__ __forceinline__ float fexp2(float x) {
#if __has_builtin(__builtin_amdgcn_exp2f)
    return __builtin_amdgcn_exp2f(x);
#else
    return exp2f(x);
#endif
}
__device__ __forceinline__ float bf2f(u16 v) {
    return __uint_as_float((uint32_t)v << 16);
}
// swap upper 32 lanes of a with lower 32 lanes of b
__device__ __forceinline__ void plswap(uint32_t& a, uint32_t& b) {
#if __has_builtin(__builtin_amdgcn_permlane32_swap)
    typedef __attribute__((ext_vector_type(2))) unsigned int uint2v;
    uint2v r = __builtin_amdgcn_permlane32_swap(a, b, false, false);
    a = r[0]; b = r[1];
#else
    asm volatile("v_permlane32_swap_b32 %0, %1" : "+v"(a), "+v"(b));
#endif
}
__device__ __forceinline__ void gload16(const void* g, void* l) {
    __builtin_amdgcn_global_load_lds(
        (const __attribute__((address_space(1))) void*)g,
        (__attribute__((address_space(3))) void*)l, 16, 0, 0);
}

// ---- fused f32->bf16 conversion: q/k/v (z<3) and weights -------------------
__global__ __launch_bounds__(256) void cvt_qw(const float* __restrict__ q,
    const float* __restrict__ k, const float* __restrict__ v,
    const float* __restrict__ w0, const float* __restrict__ w1,
    const float* __restrict__ w2, const float* __restrict__ w3,
    u16* __restrict__ xall, u16* __restrict__ wall) {
    const int bx = blockIdx.x;
    if (bx < 12288) {           // q/k/v: 3 x 4096 blocks
        int z = bx >> 12;
        size_t i = (size_t)(bx & 4095) * 256 + threadIdx.x;
        const float* src = z == 0 ? q : (z == 1 ? k : v);
        float4 f = ((const float4*)src)[i];
        ushort4 o;
        o.x = bf16rne(f.x); o.y = bf16rne(f.y);
        o.z = bf16rne(f.z); o.w = bf16rne(f.w);
        ((ushort4*)(xall + (size_t)z * kM * kHid))[i] = o;
    } else {                    // weights: 4 x 256 blocks
        int r = bx - 12288;
        int z = r >> 8;
        size_t i = (size_t)(r & 255) * 256 + threadIdx.x;
        const float* src = z == 0 ? w0 : (z == 1 ? w1 : (z == 2 ? w2 : w3));
        float sc = (z == 0)
            ? (float)(1.4426950408889634 / (6.0 * 0.6931471805599453))  // log2e/ln64
            : 1.0f;
        float4 f = ((const float4*)src)[i];
        ushort4 o;
        o.x = bf16rne(f.x * sc); o.y = bf16rne(f.y * sc);
        o.z = bf16rne(f.z * sc); o.w = bf16rne(f.w * sc);
        ((ushort4*)(wall + (size_t)z * kHid * kHid))[i] = o;
    }
}

// ---- mask -> float bias (0 or -1e30) ---------------------------------------
__global__ __launch_bounds__(256) void cvt_mask(const int* __restrict__ mask,
    float* __restrict__ fb) {
    int i = blockIdx.x * 256 + threadIdx.x;
    fb[i] = mask[i] ? 0.0f : -1e30f;
}

// ---- QKV projection: out = x @ W^T; block 128x128, wave 64x64 --------------
__global__ __launch_bounds__(256, 3) void proj(const u16* __restrict__ xall,
    const u16* __restrict__ wall, u16* __restrict__ qp, u16* __restrict__ kp,
    u16* __restrict__ vt) {
    __shared__ float smt[4][16][68];
    const int z = blockIdx.z;
    const u16* x = xall + (size_t)z * kM * kHid;
    const u16* w = wall + (size_t)z * kHid * kHid;
    const int wv = threadIdx.x >> 6, lane = threadIdx.x & 63;
    const int quad = lane >> 4, l16 = lane & 15;
    const int mb = blockIdx.y * 128 + (wv >> 1) * 64;
    const int nb = blockIdx.x * 128 + (wv & 1) * 64;
    floatx4 acc[4][4] = {};
    const u16* xr = x + (size_t)(mb + l16) * kHid + quad * 8;
    const u16* wr = w + (size_t)(nb + l16) * kHid + quad * 8;
    for (int k0 = 0; k0 < kHid; k0 += 32) {
        short8 a[4], bt[4];
#pragma unroll
        for (int i = 0; i < 4; i++)
            a[i] = *(const short8*)(xr + (size_t)i * 16 * kHid + k0);
#pragma unroll
        for (int t = 0; t < 4; t++)
            bt[t] = *(const short8*)(wr + (size_t)t * 16 * kHid + k0);
#pragma unroll
        for (int i = 0; i < 4; i++)
#pragma unroll
        for (int t = 0; t < 4; t++)
            acc[i][t] = __builtin_amdgcn_mfma_f32_16x16x32_bf16(a[i], bt[t], acc[i][t], 0, 0, 0);
    }
    if (z < 2) {
        u16* dst = (z == 0) ? qp : kp;
        const int row16 = lane >> 2, cseg = (lane & 3) * 16;
#pragma unroll
        for (int i = 0; i < 4; i++) {
#pragma unroll
            for (int t = 0; t < 4; t++)
#pragma unroll
            for (int r = 0; r < 4; r++)
                smt[wv][quad * 4 + r][t * 16 + l16] = acc[i][t][r];
            __builtin_amdgcn_wave_barrier();
            const float* rp = &smt[wv][row16][cseg];
            float4 f0 = *(const float4*)(rp);
            float4 f1 = *(const float4*)(rp + 4);
            float4 f2 = *(const float4*)(rp + 8);
            float4 f3 = *(const float4*)(rp + 12);
            uint4 o0, o1;
            o0.x = pk2(f0.x, f0.y); o0.y = pk2(f0.z, f0.w);
            o0.z = pk2(f1.x, f1.y); o0.w = pk2(f1.z, f1.w);
            o1.x = pk2(f2.x, f2.y); o1.y = pk2(f2.z, f2.w);
            o1.z = pk2(f3.x, f3.y); o1.w = pk2(f3.z, f3.w);
            u16* dp = dst + (size_t)(mb + i * 16 + row16) * kHid + nb + cseg;
            *(uint4*)dp = o0;
            *(uint4*)(dp + 8) = o1;
            __builtin_amdgcn_wave_barrier();
        }
    } else {
#pragma unroll
        for (int i = 0; i < 4; i++)
#pragma unroll
        for (int t = 0; t < 4; t++) {
            int m0 = mb + i * 16 + quad * 4;
            int n = nb + t * 16 + l16;
            int b = m0 >> 12, s = m0 & (kS - 1);
            int h = n >> 6,   d = n & (kDk - 1);
            ushort4 o;
            o.x = bf16rne(acc[i][t][0]); o.y = bf16rne(acc[i][t][1]);
            o.z = bf16rne(acc[i][t][2]); o.w = bf16rne(acc[i][t][3]);
            *(ushort4*)(vt + ((size_t)(b * kH + h) * kDk + d) * kS + s) = o;
        }
    }
}

// ---- flash attention v10 ---------------------------------------------------
// 512 blocks x 256 thr; wave owns 64 q (2 q-tiles of 32); split-K kz=0/1.
// blockIdx decode pins each bh to one XCD (wgid%8 ~ XCD round-robin).
__global__ __launch_bounds__(256, 2) void attn(const u16* __restrict__ qp,
    const u16* __restrict__ kp, const u16* __restrict__ vt,
    const float* __restrict__ fbias, u16* __restrict__ ows,
    float* __restrict__ rsws) {
    union SmT {
        struct { u16 K[2][64][64]; u16 V[2][64][64]; } s;   // 32768 B
        float ep[4][32][33];                                 // 16896 B
    };
    __shared__ __align__(16) SmT sm;
    const int tid = threadIdx.x;
    const int wv = tid >> 6, l = tid & 63;
    const int hf = l >> 5, q32 = l & 31, l7 = l & 7;
    // XCD-aware decode: bh -> fixed XCD (2 bh per XCD; K/V set = 2MB < L2)
    const int wg = blockIdx.x;
    const int bh = ((wg & 7) << 1) | ((wg >> 3) & 1);
    const int qb = (wg >> 4) & 15;
    const int kz = wg >> 8;
    const int b = bh >> 3, h = bh & 7;
    const int qbase = qb * 256 + wv * 64;
    const u16* Qb = qp + (size_t)b * kS * kHid + h * 64;   // [s][512] + h*64
    const u16* Kb = kp + (size_t)b * kS * kHid + h * 64;
    const u16* Vb = vt + (size_t)bh * kDk * kS;            // [d][s]
    const float* fm = fbias + b * kS;

    // Q frags: row = qbase+qt*32+q32, k-chunk m*16 + hf*8
    short8 qf[2][4];
#pragma unroll
    for (int qt = 0; qt < 2; qt++)
#pragma unroll
    for (int m = 0; m < 4; m++)
        qf[qt][m] = *(const short8*)(Qb + (size_t)(qbase + qt * 32 + q32) * kHid + m * 16 + hf * 8);

    floatx16 O[2][2] = {};   // [qt][d-half], C-layout
    float rs[2] = {0.0f, 0.0f};

    // staging: 16 gload16/block/tile; per-lane global source pre-swizzled so
    // linear LDS dest realizes chunk_phys = chunk ^ (row&7). Pointers advance
    // by constant stride per tile (strength-reduced).
    const int srow = l >> 3;                   // 0..7 in 8-row group
    const int pcol = (l7 ^ srow) * 8;          // swizzled source col (u16)
    const u16* pK = Kb + (size_t)(kz * 64 + wv * 8 + srow) * kHid + pcol;
    const u16* pV = Vb + (size_t)(wv * 8 + srow) * kS + kz * 64 + pcol;
    auto stage = [&](int ph) {
        gload16(pK,                        &sm.s.K[ph][wv * 8][0]);
        gload16(pK + (size_t)32 * kHid,    &sm.s.K[ph][wv * 8 + 32][0]);
        gload16(pV,                        &sm.s.V[ph][wv * 8][0]);
        gload16(pV + (size_t)32 * kS,      &sm.s.V[ph][wv * 8 + 32][0]);
        pK += (size_t)128 * kHid;          // 2 key-tiles (split-K stride)
        pV += 128;
    };

    stage(0);
    __syncthreads();

    for (int s5 = 0; s5 < 32; ++s5) {
        const int ph = s5 & 1;
        const int kt = (kz + 2 * s5) * 64;
        if (s5 < 31) stage(ph ^ 1);
#pragma unroll
        for (int ks = 0; ks < 2; ++ks) {
            // K frags: row = ks*32+q32, chunk_phys = (2m+hf)^(row&7)
            short8 kf[4];
#pragma unroll
            for (int m = 0; m < 4; m++)
                kf[m] = *(const short8*)&sm.s.K[ph][ks * 32 + q32][((2 * m + hf) ^ l7) * 8];
            // V frags: row = ds*32+q32, chunk = ks*4 + tt*2 + hf
            short8 vf[2][2];
#pragma unroll
            for (int ds = 0; ds < 2; ds++)
#pragma unroll
            for (int tt = 0; tt < 2; tt++)
                vf[ds][tt] = *(const short8*)&sm.s.V[ph][ds * 32 + q32][((ks * 4 + tt * 2 + hf) ^ l7) * 8];
            // mask bias (shared by both q-tiles): key = (r&3)+8*(r>>2)+4*hf
            const float* fp = fm + kt + ks * 32 + 4 * hf;
            float4 g0 = *(const float4*)(fp);
            float4 g1 = *(const float4*)(fp + 8);
            float4 g2 = *(const float4*)(fp + 16);
            float4 g3 = *(const float4*)(fp + 24);
#pragma unroll
            for (int qt = 0; qt < 2; ++qt) {
                floatx16 st;
                st[0] = g0.x;  st[1] = g0.y;  st[2] = g0.z;  st[3] = g0.w;
                st[4] = g1.x;  st[5] = g1.y;  st[6] = g1.z;  st[7] = g1.w;
                st[8] = g2.x;  st[9] = g2.y;  st[10] = g2.z; st[11] = g2.w;
                st[12] = g3.x; st[13] = g3.y; st[14] = g3.z; st[15] = g3.w;
                // S^T = K*Q^T + bias
#pragma unroll
                for (int m = 0; m < 4; m++)
                    st = __builtin_amdgcn_mfma_f32_32x32x16_bf16(kf[m], qf[qt][m], st, 0, 0, 0);
                // exp2 + sum
                float xx[16];
#pragma unroll
                for (int r = 0; r < 16; r++) xx[r] = fexp2(st[r]);
                rs[qt] += (((xx[0] + xx[1]) + (xx[2] + xx[3])) + ((xx[4] + xx[5]) + (xx[6] + xx[7])))
                        + (((xx[8] + xx[9]) + (xx[10] + xx[11])) + ((xx[12] + xx[13]) + (xx[14] + xx[15])));
                // pack + permlane32_swap -> PV B-frags (no LDS)
                uint32_t w00 = pk2(xx[0], xx[1]),   w01 = pk2(xx[2], xx[3]);
                uint32_t w10 = pk2(xx[4], xx[5]),   w11 = pk2(xx[6], xx[7]);
                uint32_t w20 = pk2(xx[8], xx[9]),   w21 = pk2(xx[10], xx[11]);
                uint32_t w30 = pk2(xx[12], xx[13]), w31 = pk2(xx[14], xx[15]);
                plswap(w00, w10); plswap(w01, w11);
                plswap(w20, w30); plswap(w21, w31);
                uintx4 t0 = {w00, w01, w10, w11};
                uintx4 t1 = {w20, w21, w30, w31};
                short8 bf0 = __builtin_bit_cast(short8, t0);
                short8 bf1 = __builtin_bit_cast(short8, t1);
                // O^T += V^T * P^T
                O[qt][0] = __builtin_amdgcn_mfma_f32_32x32x16_bf16(vf[0][0], bf0, O[qt][0], 0, 0, 0);
                O[qt][0] = __builtin_amdgcn_mfma_f32_32x32x16_bf16(vf[0][1], bf1, O[qt][0], 0, 0, 0);
                O[qt][1] = __builtin_amdgcn_mfma_f32_32x32x16_bf16(vf[1][0], bf0, O[qt][1], 0, 0, 0);
                O[qt][1] = __builtin_amdgcn_mfma_f32_32x32x16_bf16(vf[1][1], bf1, O[qt][1], 0, 0, 0);
            }
        }
        __syncthreads();
    }

    // partial row-sums + partial O (raw, bf16) per q-tile
#pragma unroll
    for (int qt = 0; qt < 2; ++qt) {
        float r = rs[qt];
        r += __shfl_xor(r, 32);
        if (hf == 0)
            rsws[((size_t)kz * kBH + bh) * kS + qbase + qt * 32 + q32] = r;
        u16* Ob = ows + (((size_t)kz * kBH + bh) * kS + qbase + qt * 32) * kDk;
#pragma unroll
        for (int ds = 0; ds < 2; ds++) {
#pragma unroll
            for (int rr = 0; rr < 16; rr++)
                sm.ep[wv][q32][(rr & 3) + 8 * (rr >> 2) + 4 * hf] = O[qt][ds][rr];
            __builtin_amdgcn_wave_barrier();
            {
                const int qq = l >> 1, c0 = (l & 1) * 16;
                float f[16];
#pragma unroll
                for (int j = 0; j < 16; j++) f[j] = sm.ep[wv][qq][c0 + j];
                uint4 o0, o1;
                o0.x = pk2(f[0], f[1]);   o0.y = pk2(f[2], f[3]);
                o0.z = pk2(f[4], f[5]);   o0.w = pk2(f[6], f[7]);
                o1.x = pk2(f[8], f[9]);   o1.y = pk2(f[10], f[11]);
                o1.z = pk2(f[12], f[13]); o1.w = pk2(f[14], f[15]);
                u16* dp = Ob + (size_t)qq * kDk + ds * 32 + c0;
                *(uint4*)dp = o0;
                *(uint4*)(dp + 8) = o1;
            }
            __builtin_amdgcn_wave_barrier();
        }
    }
}

// ---- combine: out = (O_part0 + O_part1) / (rs0 + rs1), bf16 ---------------
__global__ __launch_bounds__(256) void combine(const u16* __restrict__ ows,
    const float* __restrict__ rsws, u16* __restrict__ xo) {
    size_t i = (size_t)blockIdx.x * 256 + threadIdx.x;   // 524288 total
    const int d8 = (int)(i & 7);
    const int s  = (int)((i >> 3) & (kS - 1));
    const int bh = (int)(i >> 15);
    const int b = bh >> 3, h = bh & 7;
    const size_t base = ((size_t)bh * kS + s) * kDk + d8 * 8;
    short8 a = *(const short8*)(ows + base);
    short8 c = *(const short8*)(ows + (size_t)kBH * kS * kDk + base);
    float r = rsws[(size_t)bh * kS + s] + rsws[(size_t)kBH * kS + (size_t)bh * kS + s];
    float inv = 1.0f / r;
    float e[8];
#pragma unroll
    for (int j = 0; j < 8; j++)
        e[j] = (bf2f((u16)a[j]) + bf2f((u16)c[j])) * inv;
    uint4 o;
    o.x = pk2(e[0], e[1]); o.y = pk2(e[2], e[3]);
    o.z = pk2(e[4], e[5]); o.w = pk2(e[6], e[7]);
    *(uint4*)(xo + ((size_t)b * kS + s) * kHid + h * 64 + d8 * 8) = o;
}

// ---- output projection: out = X @ Wo^T; block 128x128, wave 64x64, f32 out -
__global__ __launch_bounds__(256, 3) void oproj(const u16* __restrict__ x,
    const u16* __restrict__ w, float* __restrict__ out) {
    const int wv = threadIdx.x >> 6, lane = threadIdx.x & 63;
    const int quad = lane >> 4, l16 = lane & 15;
    const int mb = blockIdx.y * 128 + (wv >> 1) * 64;
    const int nb = blockIdx.x * 128 + (wv & 1) * 64;
    floatx4 acc[4][4] = {};
    const u16* xr = x + (size_t)(mb + l16) * kHid + quad * 8;
    const u16* wr = w + (size_t)(nb + l16) * kHid + quad * 8;
    for (int k0 = 0; k0 < kHid; k0 += 32) {
        short8 a[4], bt[4];
#pragma unroll
        for (int i = 0; i < 4; i++)
            a[i] = *(const short8*)(xr + (size_t)i * 16 * kHid + k0);
#pragma unroll
        for (int t = 0; t < 4; t++)
            bt[t] = *(const short8*)(wr + (size_t)t * 16 * kHid + k0);
#pragma unroll
        for (int i = 0; i < 4; i++)
#pragma unroll
        for (int t = 0; t < 4; t++)
            acc[i][t] = __builtin_amdgcn_mfma_f32_16x16x32_bf16(a[i], bt[t], acc[i][t], 0, 0, 0);
    }
#pragma unroll
    for (int i = 0; i < 4; i++)
#pragma unroll
    for (int t = 0; t < 4; t++)
#pragma unroll
    for (int r = 0; r < 4; r++) {
        int m = mb + i * 16 + quad * 4 + r;
        int n = nb + t * 16 + l16;
        out[(size_t)m * kHid + n] = acc[i][t][r];
    }
}

} // namespace

extern "C" void kernel_launch(void* const* d_in, const int* in_sizes, int n_in,
                              void* d_out, int out_size, void* d_ws, size_t ws_size,
                              hipStream_t stream) {
    const float* q  = (const float*)d_in[0];
    const float* k  = (const float*)d_in[1];
    const float* v  = (const float*)d_in[2];
    const int* mask = (const int*)d_in[3];
    const float* w0 = (const float*)d_in[4];
    const float* w1 = (const float*)d_in[5];
    const float* w2 = (const float*)d_in[6];
    const float* w3 = (const float*)d_in[7];
    float* out = (float*)d_out;

    // ws (u16 units): xall(3x4.19M) | wall(4x256K) | Q | K | V^T  (~52.4 MB)
    // After proj, xall is dead and is reused:
    //   ows  (bf16 partial O [2][16][4096][64], 16.78 MB) at xall[0]
    //   fbias (f32, 32 KB) at xall + 2*kM*kHid (clear of ows)
    //   rsws (f32 [2][16][4096], 512 KB) after fbias
    // xo (combine output) reuses qp (dead after attn).
    u16* ws   = (u16*)d_ws;
    u16* xall = ws;
    u16* wall = xall + (size_t)3 * kM * kHid;
    u16* qp   = wall + (size_t)4 * kHid * kHid;
    u16* kp   = qp + (size_t)kBH * kS * kDk;
    u16* vt   = kp + (size_t)kBH * kS * kDk;
    u16* ows  = xall;
    float* fbias = (float*)(xall + (size_t)2 * kM * kHid);
    float* rsws  = fbias + (size_t)kB * kS;
    u16* xo   = qp;

    dim3 blk(256);
    cvt_qw <<<dim3(13312), blk, 0, stream>>>(q, k, v, w0, w1, w2, w3, xall, wall);
    proj   <<<dim3(kHid / 128, kM / 128, 3), blk, 0, stream>>>(xall, wall, qp, kp, vt);
    cvt_mask<<<dim3(kB * kS / 256), blk, 0, stream>>>(mask, fbias);
    attn   <<<dim3(512), blk, 0, stream>>>(qp, kp, vt, fbias, ows, rsws);
    combine<<<dim3(2048), blk, 0, stream>>>(ows, rsws, xo);
    oproj  <<<dim3(kHid / 128, kM / 128), blk, 0, stream>>>(
        xo, wall + (size_t)3 * kHid * kHid, out);
}